// Round 8
// baseline (225.325 us; speedup 1.0000x reference)
//
#include <hip/hip_runtime.h>

#define N 8192
#define C 64
#define S 16

static constexpr float BN_INV = 0.9999950000374997f; // 1/sqrt(1+1e-5)
static constexpr float LN_EPS = 1e-5f;

typedef _Float16 f16x8 __attribute__((ext_vector_type(8)));
typedef float f32x4 __attribute__((ext_vector_type(4)));

__device__ __forceinline__ void sort2(unsigned& x, unsigned& y)
{
    unsigned lo = min(x, y);
    unsigned hi = max(x, y);
    x = lo;
    y = hi;
}

// ---------------------------------------------------------------------------
// K1: FUSED knn + qkv (unchanged from R7). Blocks [0,1024): exact 16-NN.
// Blocks [1024,1088): MFMA-f16 qkv riding in knn's latency shadow.
// ---------------------------------------------------------------------------
__global__ __launch_bounds__(512) void qkv_knn_kernel(
    const int4* __restrict__ idx4, int* __restrict__ knn_out,
    const float* __restrict__ feats,
    const float* __restrict__ Wq, const float* __restrict__ bq,
    const float* __restrict__ Wk, const float* __restrict__ bk,
    const float* __restrict__ Wv, const float* __restrict__ bv,
    float* __restrict__ xq, float* __restrict__ xk, float* __restrict__ xv)
{
    extern __shared__ char smem[];
    const int t = threadIdx.x;
    const int lane = t & 63;
    const int wv = t >> 6;
    if (blockIdx.x < 1024) {
        unsigned* pk = (unsigned*)smem;
        const int q = blockIdx.x * 8 + wv;
#pragma unroll
        for (int i = 0; i < 16; i++) {
            int j = i * 512 + t;
            int4 c = idx4[j];
            pk[j] = (unsigned)c.y | ((unsigned)c.z << 8) |
                    ((unsigned)c.w << 16);
        }
        const int4 qc = idx4[q];
        const int qx = qc.y, qy = qc.z, qz = qc.w;
        const unsigned qq = (unsigned)(qx * qx + qy * qy + qz * qz);
#if __has_builtin(__builtin_amdgcn_udot4)
        const unsigned qpk2 = (unsigned)(2 * qx) | ((unsigned)(2 * qy) << 8) |
                              ((unsigned)(2 * qz) << 16);
#endif
        unsigned a0 = 0xFFFFFFFFu, a1 = 0xFFFFFFFFu, a2 = 0xFFFFFFFFu,
                 a3 = 0xFFFFFFFFu;
        unsigned b0 = 0xFFFFFFFFu, b1 = 0xFFFFFFFFu, b2 = 0xFFFFFFFFu,
                 b3 = 0xFFFFFFFFu;
        __syncthreads();
#pragma unroll 4
        for (int i = 0; i < 64; ++i) {
            int jA = i * 64 + lane;
            int jB = (i + 64) * 64 + lane;
            unsigned pA = pk[jA];
            unsigned pB = pk[jB];
#if __has_builtin(__builtin_amdgcn_udot4)
            unsigned d2A = __builtin_amdgcn_udot4(pA, pA, qq, false) -
                           __builtin_amdgcn_udot4(pA, qpk2, 0u, false);
            unsigned d2B = __builtin_amdgcn_udot4(pB, pB, qq, false) -
                           __builtin_amdgcn_udot4(pB, qpk2, 0u, false);
#else
            int xa = (int)(pA & 255u), ya = (int)((pA >> 8) & 255u),
                za = (int)(pA >> 16);
            int xb = (int)(pB & 255u), yb = (int)((pB >> 8) & 255u),
                zb = (int)(pB >> 16);
            int dxa = xa - qx, dya = ya - qy, dza = za - qz;
            int dxb = xb - qx, dyb = yb - qy, dzb = zb - qz;
            unsigned d2A = (unsigned)(dxa * dxa + dya * dya + dza * dza);
            unsigned d2B = (unsigned)(dxb * dxb + dyb * dyb + dzb * dzb);
#endif
            unsigned keyA = (d2A << 13) + (unsigned)jA;
            unsigned keyB = (d2B << 13) + (unsigned)jB;
            a3 = min(a3, keyA);
            sort2(a2, a3); sort2(a1, a2); sort2(a0, a1);
            b3 = min(b3, keyB);
            sort2(b2, b3); sort2(b1, b2); sort2(b0, b1);
        }
        unsigned t0 = min(a0, b3), t1 = min(a1, b2), t2 = min(a2, b1),
                 t3 = min(a3, b0);
        sort2(t0, t2); sort2(t1, t3); sort2(t0, t1); sort2(t2, t3);
        sort2(t1, t2);
        const unsigned t3pre = t3;
        unsigned g16 = 0;
        for (int r = 0; r < 16; ++r) {
            unsigned m = t0;
            m = min(m, (unsigned)__shfl_xor((int)m, 1, 64));
            m = min(m, (unsigned)__shfl_xor((int)m, 2, 64));
            m = min(m, (unsigned)__shfl_xor((int)m, 4, 64));
            m = min(m, (unsigned)__shfl_xor((int)m, 8, 64));
            m = min(m, (unsigned)__shfl_xor((int)m, 16, 64));
            m = min(m, (unsigned)__shfl_xor((int)m, 32, 64));
            if (lane == r) knn_out[q * 16 + r] = (int)(m & 8191u);
            bool win = (t0 == m);
            t0 = win ? t1 : t0;
            t1 = win ? t2 : t1;
            t2 = win ? t3 : t2;
            t3 = win ? 0xFFFFFFFFu : t3;
            g16 = m;
        }
        unsigned long long bad = __ballot(t3pre < g16);
        if (bad) {
            unsigned c0 = 0xFFFFFFFFu, c1 = 0xFFFFFFFFu, c2 = 0xFFFFFFFFu,
                     c3 = 0xFFFFFFFFu, c4 = 0xFFFFFFFFu, c5 = 0xFFFFFFFFu,
                     c6 = 0xFFFFFFFFu, c7 = 0xFFFFFFFFu, c8 = 0xFFFFFFFFu,
                     c9 = 0xFFFFFFFFu, c10 = 0xFFFFFFFFu, c11 = 0xFFFFFFFFu,
                     c12 = 0xFFFFFFFFu, c13 = 0xFFFFFFFFu, c14 = 0xFFFFFFFFu,
                     c15 = 0xFFFFFFFFu;
            for (int i = 0; i < 128; ++i) {
                int j = i * 64 + lane;
                int4 cd = idx4[j];
                int dx = cd.y - qx, dy = cd.z - qy, dz = cd.w - qz;
                unsigned d2 = (unsigned)(dx * dx + dy * dy + dz * dz);
                unsigned key = (d2 << 13) + (unsigned)j;
                c15 = min(c15, key);
                sort2(c14, c15); sort2(c13, c14); sort2(c12, c13);
                sort2(c11, c12); sort2(c10, c11); sort2(c9, c10);
                sort2(c8, c9);   sort2(c7, c8);   sort2(c6, c7);
                sort2(c5, c6);   sort2(c4, c5);   sort2(c3, c4);
                sort2(c2, c3);   sort2(c1, c2);   sort2(c0, c1);
            }
            for (int r = 0; r < 16; ++r) {
                unsigned m = c0;
                m = min(m, (unsigned)__shfl_xor((int)m, 1, 64));
                m = min(m, (unsigned)__shfl_xor((int)m, 2, 64));
                m = min(m, (unsigned)__shfl_xor((int)m, 4, 64));
                m = min(m, (unsigned)__shfl_xor((int)m, 8, 64));
                m = min(m, (unsigned)__shfl_xor((int)m, 16, 64));
                m = min(m, (unsigned)__shfl_xor((int)m, 32, 64));
                if (lane == r) knn_out[q * 16 + r] = (int)(m & 8191u);
                bool win = (c0 == m);
                c0 = win ? c1 : c0;    c1 = win ? c2 : c1;
                c2 = win ? c3 : c2;    c3 = win ? c4 : c3;
                c4 = win ? c5 : c4;    c5 = win ? c6 : c5;
                c6 = win ? c7 : c6;    c7 = win ? c8 : c7;
                c8 = win ? c9 : c8;    c9 = win ? c10 : c9;
                c10 = win ? c11 : c10; c11 = win ? c12 : c11;
                c12 = win ? c13 : c12; c13 = win ? c14 : c13;
                c14 = win ? c15 : c14; c15 = win ? 0xFFFFFFFFu : c15;
            }
        }
    } else {
        _Float16* sBt = (_Float16*)smem;
        float* sbias = (float*)(smem + 192 * 72 * 2);
        const int col = lane & 15, g = lane >> 4;
        const int bid2 = blockIdx.x - 1024;
        const int row0w = bid2 * 128 + wv * 16;
        {
            const float* Ws[3] = {Wq, Wk, Wv};
#pragma unroll
            for (int m = 0; m < 3; m++) {
                int k = t >> 3, nb = (t & 7) * 8;
                const float4* src = (const float4*)(Ws[m] + k * 64 + nb);
                float4 w0 = src[0], w1 = src[1];
                _Float16* dst = &sBt[(m * 64 + nb) * 72 + k];
                dst[0 * 72] = (_Float16)w0.x; dst[1 * 72] = (_Float16)w0.y;
                dst[2 * 72] = (_Float16)w0.z; dst[3 * 72] = (_Float16)w0.w;
                dst[4 * 72] = (_Float16)w1.x; dst[5 * 72] = (_Float16)w1.y;
                dst[6 * 72] = (_Float16)w1.z; dst[7 * 72] = (_Float16)w1.w;
            }
            if (t < 64) sbias[t] = bq[t];
            else if (t < 128) sbias[t] = bk[t - 64];
            else if (t < 192) sbias[t] = bv[t - 128];
        }
        __syncthreads();
        f16x8 au[2];
#pragma unroll
        for (int kc = 0; kc < 2; kc++) {
            const float4* src = (const float4*)
                (feats + (row0w + col) * 64 + kc * 32 + g * 8);
            float4 v0 = src[0], v1 = src[1];
            au[kc][0] = (_Float16)v0.x; au[kc][1] = (_Float16)v0.y;
            au[kc][2] = (_Float16)v0.z; au[kc][3] = (_Float16)v0.w;
            au[kc][4] = (_Float16)v1.x; au[kc][5] = (_Float16)v1.y;
            au[kc][6] = (_Float16)v1.z; au[kc][7] = (_Float16)v1.w;
        }
        float* outs[3] = {xq, xk, xv};
#pragma unroll
        for (int f = 0; f < 12; f++) {
            f32x4 acc;
            float bias = sbias[f * 16 + col];
#pragma unroll
            for (int r = 0; r < 4; r++) acc[r] = bias;
#pragma unroll
            for (int kc = 0; kc < 2; kc++) {
                f16x8 bw = *(const f16x8*)
                    &sBt[(f * 16 + col) * 72 + kc * 32 + g * 8];
                acc = __builtin_amdgcn_mfma_f32_16x16x32_f16(au[kc], bw, acc,
                                                             0, 0, 0);
            }
            float* o = outs[f >> 2];
            int cg = (f & 3) * 16 + col;
#pragma unroll
            for (int r = 0; r < 4; r++)
                o[(row0w + g * 4 + r) * 64 + cg] = acc[r];
        }
    }
}

// ---------------------------------------------------------------------------
// K2: FUSED attn + head. 1024 blocks x 512 thr; one query per wave (attn
// phase, as R7), then the 8 attn rows stay on-chip: Wc1/Wc2/Wc3 restaged
// into the SAME 17408-half slab (Ww1 stride 68 + Ww2 stride 136 fill it
// exactly; dead after GEMM2), row tiles live in the dead per-wave scratch,
// 3 MFMA layers + f32 LayerNorm epilogue. Head dispatch eliminated.
// ---------------------------------------------------------------------------
__global__ __launch_bounds__(512, 4) void attn_head_kernel(
    const int4* __restrict__ idx4, const int* __restrict__ knn,
    const float* __restrict__ xq, const float* __restrict__ xk,
    const float* __restrict__ xv,
    const float* __restrict__ Wp1, const float* __restrict__ pg,
    const float* __restrict__ pb, const float* __restrict__ Wp2,
    const float* __restrict__ bp2,
    const float* __restrict__ wg1, const float* __restrict__ wb1,
    const float* __restrict__ Ww1,
    const float* __restrict__ wg2, const float* __restrict__ wb2,
    const float* __restrict__ Ww2, const float* __restrict__ bw2,
    const float* __restrict__ feats,
    const float* __restrict__ Wc1, const float* __restrict__ cg1,
    const float* __restrict__ cb1, const float* __restrict__ Wc2,
    const float* __restrict__ cg2, const float* __restrict__ cb2,
    const float* __restrict__ Wc3, const float* __restrict__ bc3,
    const float* __restrict__ lng, const float* __restrict__ lnb,
    float* __restrict__ out)
{
    __shared__ _Float16 slab[17408];      // W1t(128x68) + W2t(64x136) / WcT
    __shared__ _Float16 sscr[8][2176];    // per-wave scratch / head tiles
    __shared__ float sWp1[48], sPg[16], sPb[16];
    __shared__ float sga1[128], sba1[128], sga2[128], sbb2[128];
    __shared__ float sbc3[64], sLg[64], sLb[64];

    _Float16* W1t = slab;            // stride 68
    _Float16* W2t = slab + 8704;     // stride 136

    const int t = threadIdx.x;
    const int lane = t & 63;
    const int wv = t >> 6;
    const int col = lane & 15, g = lane >> 4;
    const int q = blockIdx.x * 8 + wv;

    // per-query gather chain first
    const int jA = knn[q * 16 + col];
    const int4 jC = *(const int4*)(knn + q * 16 + g * 4);
    const int jr[4] = {jC.x, jC.y, jC.z, jC.w};
    const int4 pc = idx4[jA];
    const int4 qc = idx4[q];
    float xqv[4], xkv[4][4], xvv[4][4];
#pragma unroll
    for (int f = 0; f < 4; f++) xqv[f] = xq[q * 64 + f * 16 + col];
#pragma unroll
    for (int r = 0; r < 4; r++)
#pragma unroll
        for (int f = 0; f < 4; f++) {
            xkv[r][f] = xk[jr[r] * 64 + f * 16 + col];
            xvv[r][f] = xv[jr[r] * 64 + f * 16 + col];
        }
    const float featv = feats[q * 64 + lane]; // head input, coalesced

    // stage attn weights
    for (int e = t; e < 8192; e += 512) {
        int c = e >> 7, o = e & 127;
        W1t[o * 68 + c] = (_Float16)Ww1[e];
    }
    for (int e = t; e < 8192; e += 512) {
        int n = e >> 6, m = e & 63;
        W2t[m * 136 + n] = (_Float16)Ww2[e];
    }
    if (t < 48) sWp1[t] = Wp1[t];
    if (t < 16) { sPg[t] = pg[t] * BN_INV; sPb[t] = pb[t]; }
    if (t < 128) {
        sga1[t] = cg1[t] * BN_INV; sba1[t] = cb1[t];
        sga2[t] = cg2[t] * BN_INV; sbb2[t] = cb2[t];
    } else if (t < 192) {
        int o = t - 128;
        sbc3[o] = bc3[o]; sLg[o] = lng[o]; sLb[o] = lnb[o];
    }

    float g1c[4], b1c[4], bp2c[4], bw2c[4], g2c[8], b2c[8];
#pragma unroll
    for (int f = 0; f < 4; f++) {
        int c = f * 16 + col;
        g1c[f] = wg1[c] * BN_INV; b1c[f] = wb1[c];
        bp2c[f] = bp2[c]; bw2c[f] = bw2[c];
    }
#pragma unroll
    for (int f = 0; f < 8; f++) {
        int o = f * 16 + col;
        g2c[f] = wg2[o] * BN_INV; b2c[f] = wb2[o];
    }
    f16x8 bP[4];
#pragma unroll
    for (int f = 0; f < 4; f++) {
#pragma unroll
        for (int j = 0; j < 8; j++) {
            int h = g * 8 + j;
            bP[f][j] = (g < 2) ? (_Float16)Wp2[h * 64 + f * 16 + col]
                               : (_Float16)0.f;
        }
    }
    __syncthreads();

    _Float16* scr = sscr[wv];

    // ---- p_r ----
    const float px = (float)(pc.y - qc.y);
    const float py = (float)(pc.z - qc.z);
    const float pz = (float)(pc.w - qc.w);
    f16x8 aph;
#pragma unroll
    for (int j = 0; j < 8; j++) {
        int h = g * 8 + j;
        float v = 0.f;
        if (g < 2) {
            v = px * sWp1[h] + py * sWp1[16 + h] + pz * sWp1[32 + h];
            v = fmaxf(v * sPg[h] + sPb[h], 0.f);
        }
        aph[j] = (_Float16)v;
    }
    f32x4 pr[4];
#pragma unroll
    for (int f = 0; f < 4; f++) {
        f32x4 cini;
#pragma unroll
        for (int r = 0; r < 4; r++) cini[r] = bp2c[f];
        pr[f] = __builtin_amdgcn_mfma_f32_16x16x32_f16(aph, bP[f], cini,
                                                       0, 0, 0);
    }
    // ---- u / v ----
    f32x4 vvr[4];
#pragma unroll
    for (int r = 0; r < 4; r++) {
#pragma unroll
        for (int f = 0; f < 4; f++) {
            float w0 = xkv[r][f] - xqv[f] + pr[f][r];
            float uu = fmaxf(w0 * g1c[f] + b1c[f], 0.f);
            scr[(g * 4 + r) * 72 + f * 16 + col] = (_Float16)uu;
            vvr[f][r] = xvv[r][f] + pr[f][r];
        }
    }
    // ---- GEMM1 ----
    f16x8 au[2];
#pragma unroll
    for (int kc = 0; kc < 2; kc++)
        au[kc] = *(const f16x8*)&scr[col * 72 + kc * 32 + g * 8];
    f32x4 acc1[8];
#pragma unroll
    for (int f = 0; f < 8; f++)
#pragma unroll
        for (int r = 0; r < 4; r++) acc1[f][r] = 0.f;
#pragma unroll
    for (int kc = 0; kc < 2; kc++) {
#pragma unroll
        for (int f = 0; f < 8; f++) {
            f16x8 bw = *(const f16x8*)
                &W1t[(f * 16 + col) * 68 + kc * 32 + g * 8];
            acc1[f] = __builtin_amdgcn_mfma_f32_16x16x32_f16(au[kc], bw,
                                                             acc1[f], 0, 0, 0);
        }
    }
#pragma unroll
    for (int f = 0; f < 8; f++)
#pragma unroll
        for (int r = 0; r < 4; r++) {
            float o1 = fmaxf(acc1[f][r] * g2c[f] + b2c[f], 0.f);
            scr[(g * 4 + r) * 136 + f * 16 + col] = (_Float16)o1;
        }
    // ---- GEMM2 ----
    f16x8 ao[4];
#pragma unroll
    for (int kc = 0; kc < 4; kc++)
        ao[kc] = *(const f16x8*)&scr[col * 136 + kc * 32 + g * 8];
    f32x4 accL[4];
#pragma unroll
    for (int f = 0; f < 4; f++)
#pragma unroll
        for (int r = 0; r < 4; r++) accL[f][r] = bw2c[f];
#pragma unroll
    for (int kc = 0; kc < 4; kc++) {
#pragma unroll
        for (int f = 0; f < 4; f++) {
            f16x8 bw = *(const f16x8*)
                &W2t[(f * 16 + col) * 136 + kc * 32 + g * 8];
            accL[f] = __builtin_amdgcn_mfma_f32_16x16x32_f16(ao[kc], bw,
                                                             accL[f], 0, 0, 0);
        }
    }
    // ---- softmax + einsum -> attn value for channel `lane` of row q ----
    float outv[4];
#pragma unroll
    for (int f = 0; f < 4; f++) {
        float mx = fmaxf(fmaxf(accL[f][0], accL[f][1]),
                         fmaxf(accL[f][2], accL[f][3]));
        mx = fmaxf(mx, __shfl_xor(mx, 16, 64));
        mx = fmaxf(mx, __shfl_xor(mx, 32, 64));
        float sum = 0.f, part = 0.f;
#pragma unroll
        for (int r = 0; r < 4; r++) {
            float e = __expf(accL[f][r] - mx);
            sum += e;
            part = fmaf(e, vvr[f][r], part);
        }
        sum += __shfl_xor(sum, 16, 64);
        sum += __shfl_xor(sum, 32, 64);
        part += __shfl_xor(part, 16, 64);
        part += __shfl_xor(part, 32, 64);
        outv[f] = part / sum;
    }
    float aval = (g == 0) ? outv[0]
               : (g == 1) ? outv[1]
               : (g == 2) ? outv[2] : outv[3];

    // ================= HEAD PHASE (block-cooperative) =================
    _Float16* hrows = sscr[0];                 // 16 x 136 (rows 8-15 zero)
    _Float16* h1 = sscr[0] + 2176;             // 16 x 136
    _Float16* h2 = sscr[0] + 4352;             // 16 x 136
    float* h3 = (float*)(sscr[0] + 6528);      // 16 x 68 f32

    __syncthreads(); // all waves done with slab + scr
    // write row tiles + zero pad rows; stage Wc1 -> slab (stride 136)
    hrows[wv * 136 + lane] = (_Float16)featv;
    hrows[wv * 136 + 64 + lane] = (_Float16)aval;
    hrows[(8 + wv) * 136 + lane] = (_Float16)0.f;
    hrows[(8 + wv) * 136 + 64 + lane] = (_Float16)0.f;
    {
        int c = t >> 2, ob = (t & 3) * 32;
        const float4* src = (const float4*)(Wc1 + c * 128 + ob);
#pragma unroll
        for (int i = 0; i < 8; i++) {
            float4 w = src[i];
            _Float16* d = &slab[(ob + i * 4) * 136 + c];
            d[0 * 136] = (_Float16)w.x; d[1 * 136] = (_Float16)w.y;
            d[2 * 136] = (_Float16)w.z; d[3 * 136] = (_Float16)w.w;
        }
    }
    __syncthreads();
    // L1: h1 = relu(bn(hrows @ Wc1)); wave wv -> output cols wv*16..
    {
        f16x8 ax[4];
#pragma unroll
        for (int kc = 0; kc < 4; kc++)
            ax[kc] = *(const f16x8*)&hrows[col * 136 + kc * 32 + g * 8];
        f32x4 acc;
#pragma unroll
        for (int r = 0; r < 4; r++) acc[r] = 0.f;
        int n0 = wv * 16;
#pragma unroll
        for (int kc = 0; kc < 4; kc++) {
            f16x8 bw = *(const f16x8*)&slab[(n0 + col) * 136 + kc * 32 + g * 8];
            acc = __builtin_amdgcn_mfma_f32_16x16x32_f16(ax[kc], bw, acc,
                                                         0, 0, 0);
        }
        float gn = sga1[n0 + col], bs = sba1[n0 + col];
#pragma unroll
        for (int r = 0; r < 4; r++)
            h1[(g * 4 + r) * 136 + n0 + col] =
                (_Float16)fmaxf(acc[r] * gn + bs, 0.f);
    }
    __syncthreads();
    {
        int c = t >> 2, ob = (t & 3) * 32;
        const float4* src = (const float4*)(Wc2 + c * 128 + ob);
#pragma unroll
        for (int i = 0; i < 8; i++) {
            float4 w = src[i];
            _Float16* d = &slab[(ob + i * 4) * 136 + c];
            d[0 * 136] = (_Float16)w.x; d[1 * 136] = (_Float16)w.y;
            d[2 * 136] = (_Float16)w.z; d[3 * 136] = (_Float16)w.w;
        }
    }
    __syncthreads();
    // L2: h2 = relu(bn(h1 @ Wc2))
    {
        f16x8 ax[4];
#pragma unroll
        for (int kc = 0; kc < 4; kc++)
            ax[kc] = *(const f16x8*)&h1[col * 136 + kc * 32 + g * 8];
        f32x4 acc;
#pragma unroll
        for (int r = 0; r < 4; r++) acc[r] = 0.f;
        int n0 = wv * 16;
#pragma unroll
        for (int kc = 0; kc < 4; kc++) {
            f16x8 bw = *(const f16x8*)&slab[(n0 + col) * 136 + kc * 32 + g * 8];
            acc = __builtin_amdgcn_mfma_f32_16x16x32_f16(ax[kc], bw, acc,
                                                         0, 0, 0);
        }
        float gn = sga2[n0 + col], bs = sbb2[n0 + col];
#pragma unroll
        for (int r = 0; r < 4; r++)
            h2[(g * 4 + r) * 136 + n0 + col] =
                (_Float16)fmaxf(acc[r] * gn + bs, 0.f);
    }
    __syncthreads();
    {
        int c = t >> 2, ob = (t & 3) * 16;
        const float4* src = (const float4*)(Wc3 + c * 64 + ob);
#pragma unroll
        for (int i = 0; i < 4; i++) {
            float4 w = src[i];
            _Float16* d = &slab[(ob + i * 4) * 136 + c];
            d[0 * 136] = (_Float16)w.x; d[1 * 136] = (_Float16)w.y;
            d[2 * 136] = (_Float16)w.z; d[3 * 136] = (_Float16)w.w;
        }
    }
    __syncthreads();
    // L3: h3 = h2 @ Wc3 + bc3 (waves 0-3)
    if (wv < 4) {
        f16x8 ax[4];
#pragma unroll
        for (int kc = 0; kc < 4; kc++)
            ax[kc] = *(const f16x8*)&h2[col * 136 + kc * 32 + g * 8];
        int n0 = wv * 16;
        f32x4 acc;
        float bias = sbc3[n0 + col];
#pragma unroll
        for (int r = 0; r < 4; r++) acc[r] = bias;
#pragma unroll
        for (int kc = 0; kc < 4; kc++) {
            f16x8 bw = *(const f16x8*)&slab[(n0 + col) * 136 + kc * 32 + g * 8];
            acc = __builtin_amdgcn_mfma_f32_16x16x32_f16(ax[kc], bw, acc,
                                                         0, 0, 0);
        }
#pragma unroll
        for (int r = 0; r < 4; r++)
            h3[(g * 4 + r) * 68 + n0 + col] = acc[r];
    }
    __syncthreads();
    // LN: wave wv handles its own row q
    {
        float v = h3[wv * 68 + lane];
        float s1 = v, s2 = v * v;
#pragma unroll
        for (int d = 1; d < 64; d <<= 1) {
            s1 += __shfl_xor(s1, d, 64);
            s2 += __shfl_xor(s2, d, 64);
        }
        float m = s1 * (1.f / 64.f);
        float var = s2 * (1.f / 64.f) - m * m;
        float inv = 1.f / sqrtf(var + LN_EPS);
        out[q * 64 + lane] = (v - m) * inv * sLg[lane] + sLb[lane];
    }
}

// ---------------------------------------------------------------------------
extern "C" void kernel_launch(void* const* d_in, const int* in_sizes, int n_in,
                              void* d_out, int out_size, void* d_ws,
                              size_t ws_size, hipStream_t stream)
{
    const int* indices = (const int*)d_in[0];
    const float* feats = (const float*)d_in[1];
    const float* Wq = (const float*)d_in[2];
    const float* bq = (const float*)d_in[3];
    const float* Wk = (const float*)d_in[4];
    const float* bk = (const float*)d_in[5];
    const float* Wv = (const float*)d_in[6];
    const float* bv = (const float*)d_in[7];
    const float* Wp1 = (const float*)d_in[8];
    const float* pg = (const float*)d_in[9];
    const float* pb = (const float*)d_in[10];
    const float* Wp2 = (const float*)d_in[11];
    const float* bp2 = (const float*)d_in[12];
    const float* wg1 = (const float*)d_in[13];
    const float* wb1 = (const float*)d_in[14];
    const float* Ww1 = (const float*)d_in[15];
    const float* wg2 = (const float*)d_in[16];
    const float* wb2 = (const float*)d_in[17];
    const float* Ww2 = (const float*)d_in[18];
    const float* bw2 = (const float*)d_in[19];
    const float* Wc1 = (const float*)d_in[20];
    const float* cg1 = (const float*)d_in[21];
    const float* cb1 = (const float*)d_in[22];
    const float* Wc2 = (const float*)d_in[23];
    const float* cg2 = (const float*)d_in[24];
    const float* cb2 = (const float*)d_in[25];
    const float* Wc3 = (const float*)d_in[26];
    const float* bc3 = (const float*)d_in[27];
    const float* lng = (const float*)d_in[28];
    const float* lnb = (const float*)d_in[29];

    float* out = (float*)d_out;
    float* ws = (float*)d_ws;
    float* xq = ws;
    float* xk = xq + N * C;
    float* xv = xk + N * C;
    int* knn = (int*)(xv + N * C);

    qkv_knn_kernel<<<1088, 512, 32768, stream>>>(
        (const int4*)indices, knn, feats, Wq, bq, Wk, bk, Wv, bv, xq, xk, xv);
    attn_head_kernel<<<1024, 512, 0, stream>>>(
        (const int4*)indices, knn, xq, xk, xv, Wp1, pg, pb, Wp2, bp2, wg1,
        wb1, Ww1, wg2, wb2, Ww2, bw2, feats, Wc1, cg1, cb1, Wc2, cg2, cb2,
        Wc3, bc3, lng, lnb, out);
}